// Round 1
// baseline (453.413 us; speedup 1.0000x reference)
//
#include <hip/hip_runtime.h>
#include <stdint.h>
#include <math.h>

// ---------- types ----------
typedef short s16x8 __attribute__((ext_vector_type(8)));   // 8 bf16 (4 VGPR)
typedef float f32x4 __attribute__((ext_vector_type(4)));
typedef unsigned short u16x8 __attribute__((ext_vector_type(8)));

__device__ __forceinline__ unsigned short f2bf(float f) {
    union { float f; uint32_t u; } x; x.f = f;
    uint32_t r = x.u + 0x7FFFu + ((x.u >> 16) & 1u);   // RNE
    return (unsigned short)(r >> 16);
}

#define GLD_LDS16(gp, lp) __builtin_amdgcn_global_load_lds( \
    (const __attribute__((address_space(1))) uint32_t*)(gp), \
    (__attribute__((address_space(3))) uint32_t*)(lp), 16, 0, 0)

#define MFMA16x16x32(a, b, c) __builtin_amdgcn_mfma_f32_16x16x32_bf16((a), (b), (c), 0, 0, 0)

// ---------- convert kernels ----------
// x (f32, [BT][1024]) -> bf16
__global__ void cvt_x_kernel(const float* __restrict__ x, unsigned short* __restrict__ xb, int n) {
    int i = (blockIdx.x * blockDim.x + threadIdx.x) * 4;
    if (i >= n) return;
    float4 v = *(const float4*)(x + i);
    unsigned short o0 = f2bf(v.x), o1 = f2bf(v.y), o2 = f2bf(v.z), o3 = f2bf(v.w);
    uint64_t packed = (uint64_t)o0 | ((uint64_t)o1 << 16) | ((uint64_t)o2 << 32) | ((uint64_t)o3 << 48);
    *(uint64_t*)(xb + i) = packed;
}

// W [16][1024][64] f32 -> Wt rows (which*1024 + h*64 + d), cols c  (B^T layout [.. ][1024])
__global__ void cvt_wqkv_kernel(const float* __restrict__ W, unsigned short* __restrict__ Wt, int which) {
    int id = blockIdx.x * blockDim.x + threadIdx.x;          // 16*1024*64 = 1,048,576
    if (id >= 16 * 1024 * 64) return;
    int h = id >> 16, c = (id >> 6) & 1023, d = id & 63;
    Wt[(size_t)(which * 1024 + h * 64 + d) * 1024 + c] = f2bf(W[id]);
}

// Wp [1024][1024] (c, n) -> Wpt [n][c] bf16
__global__ void cvt_wp_kernel(const float* __restrict__ W, unsigned short* __restrict__ Wt) {
    int id = blockIdx.x * blockDim.x + threadIdx.x;          // 1,048,576
    if (id >= 1024 * 1024) return;
    int c = id >> 10, n = id & 1023;
    Wt[(size_t)n * 1024 + c] = f2bf(W[id]);
}

// ---------- GEMM: C[M][N] = A[M][K] * Bt[N][K]^T  (bf16 in, bf16 or f32+bias out) ----------
template<int FOUT>
__global__ __launch_bounds__(256) void gemm_bt_kernel(
    const unsigned short* __restrict__ A, const unsigned short* __restrict__ Bt,
    void* __restrict__ Cv, const float* __restrict__ bias, int M, int N, int K)
{
    constexpr int BK = 64;
    __shared__ __align__(16) unsigned short As[128 * BK];   // 16 KB
    __shared__ __align__(16) unsigned short Bs[128 * BK];   // 16 KB
    const int t = threadIdx.x, w = t >> 6, l = t & 63, lr = l & 15, lg = l >> 4;
    const int wm = (w >> 1) << 6, wn = (w & 1) << 6;
    const int bm = blockIdx.x << 7, bn = blockIdx.y << 7;
    const unsigned short* Ab = A + (size_t)bm * K;
    const unsigned short* Bb = Bt + (size_t)bn * K;
    f32x4 acc[4][4] = {};
    for (int k0 = 0; k0 < K; k0 += BK) {
        __syncthreads();
        #pragma unroll
        for (int i = 0; i < 4; ++i) {
            int c = i * 256 + t;
            GLD_LDS16(Ab + (size_t)(c >> 3) * K + k0 + ((c & 7) << 3), As + c * 8);
        }
        #pragma unroll
        for (int i = 0; i < 4; ++i) {
            int c = i * 256 + t;
            GLD_LDS16(Bb + (size_t)(c >> 3) * K + k0 + ((c & 7) << 3), Bs + c * 8);
        }
        __syncthreads();
        #pragma unroll
        for (int ks = 0; ks < 2; ++ks) {
            s16x8 af[4], bfr[4];
            #pragma unroll
            for (int mi = 0; mi < 4; ++mi)
                af[mi] = *(const s16x8*)&As[(wm + mi * 16 + lr) * BK + ks * 32 + lg * 8];
            #pragma unroll
            for (int ni = 0; ni < 4; ++ni)
                bfr[ni] = *(const s16x8*)&Bs[(wn + ni * 16 + lr) * BK + ks * 32 + lg * 8];
            #pragma unroll
            for (int mi = 0; mi < 4; ++mi)
                #pragma unroll
                for (int ni = 0; ni < 4; ++ni)
                    acc[mi][ni] = MFMA16x16x32(af[mi], bfr[ni], acc[mi][ni]);
        }
    }
    // epilogue: C/D layout col = lane&15, row = (lane>>4)*4 + reg
    if (FOUT) {
        float* C = (float*)Cv;
        #pragma unroll
        for (int mi = 0; mi < 4; ++mi)
            #pragma unroll
            for (int ni = 0; ni < 4; ++ni) {
                int col = bn + wn + ni * 16 + lr;
                float bv = bias ? bias[col] : 0.0f;
                #pragma unroll
                for (int r = 0; r < 4; ++r) {
                    int row = bm + wm + mi * 16 + lg * 4 + r;
                    C[(size_t)row * N + col] = acc[mi][ni][r] + bv;
                }
            }
    } else {
        unsigned short* C = (unsigned short*)Cv;
        #pragma unroll
        for (int mi = 0; mi < 4; ++mi)
            #pragma unroll
            for (int ni = 0; ni < 4; ++ni) {
                int col = bn + wn + ni * 16 + lr;
                #pragma unroll
                for (int r = 0; r < 4; ++r) {
                    int row = bm + wm + mi * 16 + lg * 4 + r;
                    C[(size_t)row * N + col] = f2bf(acc[mi][ni][r]);
                }
            }
    }
}

// ---------- flash attention ----------
// qkv [B*T][3072] bf16 (cols: 0..1023 Q, 1024..2047 K, 2048..3071 V; within: h*64+d)
// attn [B*T][1024] bf16 output (h*64+d)
// block = 256 threads = 4 waves; each block: one (b, h, 64 q-rows); wave w: 16 q-rows
__global__ __launch_bounds__(256) void attn_kernel(
    const unsigned short* __restrict__ qkv, unsigned short* __restrict__ attn, int T)
{
    __shared__ __align__(16) unsigned short Ks[64 * 64];     // [s][d] 8 KB
    __shared__ __align__(16) unsigned short Vt[64 * 64];     // [d][s] 8 KB
    __shared__ __align__(16) unsigned short Ps[4][16 * 64];  // per-wave P [qrow][s] 8 KB

    const int blk = blockIdx.x;
    const int qt = blk & 31;             // T/64 = 32
    const int h  = (blk >> 5) & 15;
    const int b  = blk >> 9;
    const int q0 = qt * 64;
    const int t = threadIdx.x, w = t >> 6, l = t & 63, lr = l & 15, lg = l >> 4;
    const unsigned short* base = qkv + (size_t)b * T * 3072;
    const float scale_l2e = 0.03125f * 1.44269504088896341f;  // C^-0.5 * log2(e)

    // Q fragments (A-operand): row = lr, k = d = ks*32 + lg*8 + j
    s16x8 qf[2];
    #pragma unroll
    for (int ks = 0; ks < 2; ++ks)
        qf[ks] = *(const s16x8*)(base + (size_t)(q0 + w * 16 + lr) * 3072 + h * 64 + ks * 32 + lg * 8);

    f32x4 o[4] = {};
    float m_r[4], l_r[4];
    #pragma unroll
    for (int r = 0; r < 4; ++r) { m_r[r] = -1e30f; l_r[r] = 0.0f; }

    const int nkv = (q0 >> 6) + 1;       // causal: tiles up to & including diagonal
    for (int kt = 0; kt < nkv; ++kt) {
        const int s0 = kt * 64;
        __syncthreads();                 // prev iter's K/V reads done
        // stage K tile [64 s][64 d] linear (global_load_lds)
        #pragma unroll
        for (int i = 0; i < 2; ++i) {
            int c = i * 256 + t;
            GLD_LDS16(base + (size_t)(s0 + (c >> 3)) * 3072 + 1024 + h * 64 + ((c & 7) << 3), Ks + c * 8);
        }
        // stage V transposed: Vt[d][s]
        {
            int s = t & 63, d0 = (t >> 6) * 16;
            const unsigned short* vp = base + (size_t)(s0 + s) * 3072 + 2048 + h * 64 + d0;
            u16x8 v0 = *(const u16x8*)vp;
            u16x8 v1 = *(const u16x8*)(vp + 8);
            #pragma unroll
            for (int j = 0; j < 8; ++j) Vt[(d0 + j) * 64 + s] = v0[j];
            #pragma unroll
            for (int j = 0; j < 8; ++j) Vt[(d0 + 8 + j) * 64 + s] = v1[j];
        }
        __syncthreads();                 // staged (compiler drains vmcnt/lgkmcnt)

        // S = Q K^T : 4 col-blocks of 16 kv each
        f32x4 S[4] = {};
        #pragma unroll
        for (int nb = 0; nb < 4; ++nb)
            #pragma unroll
            for (int ks = 0; ks < 2; ++ks) {
                s16x8 kf = *(const s16x8*)&Ks[(nb * 16 + lr) * 64 + ks * 32 + lg * 8];
                S[nb] = MFMA16x16x32(qf[ks], kf, S[nb]);
            }

        // scale + causal mask, exp2 domain
        float z[4][4];
        #pragma unroll
        for (int nb = 0; nb < 4; ++nb)
            #pragma unroll
            for (int r = 0; r < 4; ++r) {
                int scol = s0 + nb * 16 + lr;
                int qrow = q0 + w * 16 + lg * 4 + r;
                z[nb][r] = (scol <= qrow) ? S[nb][r] * scale_l2e : -1e30f;
            }
        // online softmax (rows replicated across the 16 lanes of each lg-group)
        float zmax[4], alpha[4];
        #pragma unroll
        for (int r = 0; r < 4; ++r) {
            zmax[r] = fmaxf(fmaxf(z[0][r], z[1][r]), fmaxf(z[2][r], z[3][r]));
            #pragma unroll
            for (int msk = 1; msk <= 8; msk <<= 1)
                zmax[r] = fmaxf(zmax[r], __shfl_xor(zmax[r], msk, 64));
            float mnew = fmaxf(m_r[r], zmax[r]);
            alpha[r] = exp2f(m_r[r] - mnew);
            m_r[r] = mnew;
        }
        float rs[4] = {0.f, 0.f, 0.f, 0.f};
        #pragma unroll
        for (int nb = 0; nb < 4; ++nb)
            #pragma unroll
            for (int r = 0; r < 4; ++r) {
                float p = exp2f(z[nb][r] - m_r[r]);
                rs[r] += p;
                Ps[w][(lg * 4 + r) * 64 + nb * 16 + lr] = f2bf(p);
            }
        #pragma unroll
        for (int r = 0; r < 4; ++r) {
            #pragma unroll
            for (int msk = 1; msk <= 8; msk <<= 1)
                rs[r] += __shfl_xor(rs[r], msk, 64);
            l_r[r] = l_r[r] * alpha[r] + rs[r];
        }
        #pragma unroll
        for (int db = 0; db < 4; ++db)
            #pragma unroll
            for (int r = 0; r < 4; ++r)
                o[db][r] *= alpha[r];

        // P (LDS) as A-frags; V^T as B-frags
        asm volatile("s_waitcnt lgkmcnt(0)" ::: "memory");
        __builtin_amdgcn_sched_barrier(0);
        s16x8 pf[2];
        #pragma unroll
        for (int ks2 = 0; ks2 < 2; ++ks2)
            pf[ks2] = *(const s16x8*)&Ps[w][lr * 64 + ks2 * 32 + lg * 8];
        #pragma unroll
        for (int db = 0; db < 4; ++db)
            #pragma unroll
            for (int ks2 = 0; ks2 < 2; ++ks2) {
                s16x8 vf = *(const s16x8*)&Vt[(db * 16 + lr) * 64 + ks2 * 32 + lg * 8];
                o[db] = MFMA16x16x32(pf[ks2], vf, o[db]);
            }
    }

    // epilogue: out = o / l
    #pragma unroll
    for (int db = 0; db < 4; ++db)
        #pragma unroll
        for (int r = 0; r < 4; ++r) {
            int row = q0 + w * 16 + lg * 4 + r;
            int col = h * 64 + db * 16 + lr;
            attn[(size_t)(b * T + row) * 1024 + col] = f2bf(o[db][r] / l_r[r]);
        }
}

// ---------- launch ----------
extern "C" void kernel_launch(void* const* d_in, const int* in_sizes, int n_in,
                              void* d_out, int out_size, void* d_ws, size_t ws_size,
                              hipStream_t stream) {
    const float* x  = (const float*)d_in[0];
    const float* Wq = (const float*)d_in[1];
    const float* Wk = (const float*)d_in[2];
    const float* Wv = (const float*)d_in[3];
    const float* Wp = (const float*)d_in[4];
    const float* bp = (const float*)d_in[5];
    float* out = (float*)d_out;

    const int T = 2048, C = 1024;
    const int BT = in_sizes[0] / C;      // 8192
    const int B  = BT / T;               // 4

    // workspace layout (bytes)
    char* ws = (char*)d_ws;
    unsigned short* xb    = (unsigned short*)(ws);                        // 16,777,216
    unsigned short* WtQKV = (unsigned short*)(ws + 16777216);             //  6,291,456
    unsigned short* WtP   = (unsigned short*)(ws + 23068672);             //  2,097,152
    unsigned short* qkv   = (unsigned short*)(ws + 25165824);             // 50,331,648
    unsigned short* attn  = (unsigned short*)(ws + 75497472);             // 16,777,216
    (void)ws_size; (void)n_in; (void)out_size;

    // converts
    cvt_x_kernel<<<(BT * C / 4 + 255) / 256, 256, 0, stream>>>(x, xb, BT * C);
    cvt_wqkv_kernel<<<4096, 256, 0, stream>>>(Wq, WtQKV, 0);
    cvt_wqkv_kernel<<<4096, 256, 0, stream>>>(Wk, WtQKV, 1);
    cvt_wqkv_kernel<<<4096, 256, 0, stream>>>(Wv, WtQKV, 2);
    cvt_wp_kernel<<<4096, 256, 0, stream>>>(Wp, WtP);

    // QKV projection: [8192][1024] x [3072][1024]^T -> [8192][3072] bf16
    gemm_bt_kernel<0><<<dim3(BT / 128, 3072 / 128), 256, 0, stream>>>(
        xb, WtQKV, qkv, nullptr, BT, 3072, C);

    // flash attention
    attn_kernel<<<B * 16 * (T / 64), 256, 0, stream>>>(qkv, attn, T);

    // output projection: [8192][1024] x [1024][1024]^T + bias -> f32
    gemm_bt_kernel<1><<<dim3(BT / 128, 1024 / 128), 256, 0, stream>>>(
        attn, WtP, out, bp, BT, 1024, C);
}

// Round 2
// 335.320 us; speedup vs baseline: 1.3522x; 1.3522x over previous
//
#include <hip/hip_runtime.h>
#include <stdint.h>
#include <math.h>

// ---------- types ----------
typedef short s16x8 __attribute__((ext_vector_type(8)));   // 8 bf16 (4 VGPR)
typedef float f32x4 __attribute__((ext_vector_type(4)));
typedef unsigned short u16x8 __attribute__((ext_vector_type(8)));

__device__ __forceinline__ unsigned short f2bf(float f) {
    union { float f; uint32_t u; } x; x.f = f;
    uint32_t r = x.u + 0x7FFFu + ((x.u >> 16) & 1u);   // RNE
    return (unsigned short)(r >> 16);
}

#define GLD_LDS16(gp, lp) __builtin_amdgcn_global_load_lds( \
    (const __attribute__((address_space(1))) uint32_t*)(gp), \
    (__attribute__((address_space(3))) uint32_t*)(lp), 16, 0, 0)

#define MFMA16x16x32(a, b, c) __builtin_amdgcn_mfma_f32_16x16x32_bf16((a), (b), (c), 0, 0, 0)

// ---------- convert kernels ----------
__global__ void cvt_x_kernel(const float* __restrict__ x, unsigned short* __restrict__ xb, int n) {
    int i = (blockIdx.x * blockDim.x + threadIdx.x) * 4;
    if (i >= n) return;
    float4 v = *(const float4*)(x + i);
    unsigned short o0 = f2bf(v.x), o1 = f2bf(v.y), o2 = f2bf(v.z), o3 = f2bf(v.w);
    uint64_t packed = (uint64_t)o0 | ((uint64_t)o1 << 16) | ((uint64_t)o2 << 32) | ((uint64_t)o3 << 48);
    *(uint64_t*)(xb + i) = packed;
}

// W [16][1024][64] f32 -> Wt rows (which*1024 + h*64 + d), cols c  (B^T layout [..][1024])
__global__ void cvt_wqkv_kernel(const float* __restrict__ W, unsigned short* __restrict__ Wt, int which) {
    int id = blockIdx.x * blockDim.x + threadIdx.x;
    if (id >= 16 * 1024 * 64) return;
    int h = id >> 16, c = (id >> 6) & 1023, d = id & 63;
    Wt[(size_t)(which * 1024 + h * 64 + d) * 1024 + c] = f2bf(W[id]);
}

// Wp [1024][1024] (c, n) -> Wpt [n][c] bf16
__global__ void cvt_wp_kernel(const float* __restrict__ W, unsigned short* __restrict__ Wt) {
    int id = blockIdx.x * blockDim.x + threadIdx.x;
    if (id >= 1024 * 1024) return;
    int c = id >> 10, n = id & 1023;
    Wt[(size_t)n * 1024 + c] = f2bf(W[id]);
}

// ---------- GEMM: C[M][N] = A[M][K] * Bt[N][K]^T ----------
template<int FOUT>
__global__ __launch_bounds__(256) void gemm_bt_kernel(
    const unsigned short* __restrict__ A, const unsigned short* __restrict__ Bt,
    void* __restrict__ Cv, const float* __restrict__ bias, int M, int N, int K)
{
    constexpr int BK = 64;
    __shared__ __align__(16) unsigned short As[128 * BK];
    __shared__ __align__(16) unsigned short Bs[128 * BK];
    const int t = threadIdx.x, w = t >> 6, l = t & 63, lr = l & 15, lg = l >> 4;
    const int wm = (w >> 1) << 6, wn = (w & 1) << 6;
    const int bm = blockIdx.x << 7, bn = blockIdx.y << 7;
    const unsigned short* Ab = A + (size_t)bm * K;
    const unsigned short* Bb = Bt + (size_t)bn * K;
    f32x4 acc[4][4] = {};
    for (int k0 = 0; k0 < K; k0 += BK) {
        __syncthreads();
        #pragma unroll
        for (int i = 0; i < 4; ++i) {
            int c = i * 256 + t;
            GLD_LDS16(Ab + (size_t)(c >> 3) * K + k0 + ((c & 7) << 3), As + c * 8);
        }
        #pragma unroll
        for (int i = 0; i < 4; ++i) {
            int c = i * 256 + t;
            GLD_LDS16(Bb + (size_t)(c >> 3) * K + k0 + ((c & 7) << 3), Bs + c * 8);
        }
        __syncthreads();
        #pragma unroll
        for (int ks = 0; ks < 2; ++ks) {
            s16x8 af[4], bfr[4];
            #pragma unroll
            for (int mi = 0; mi < 4; ++mi)
                af[mi] = *(const s16x8*)&As[(wm + mi * 16 + lr) * BK + ks * 32 + lg * 8];
            #pragma unroll
            for (int ni = 0; ni < 4; ++ni)
                bfr[ni] = *(const s16x8*)&Bs[(wn + ni * 16 + lr) * BK + ks * 32 + lg * 8];
            #pragma unroll
            for (int mi = 0; mi < 4; ++mi)
                #pragma unroll
                for (int ni = 0; ni < 4; ++ni)
                    acc[mi][ni] = MFMA16x16x32(af[mi], bfr[ni], acc[mi][ni]);
        }
    }
    if (FOUT) {
        float* C = (float*)Cv;
        #pragma unroll
        for (int mi = 0; mi < 4; ++mi)
            #pragma unroll
            for (int ni = 0; ni < 4; ++ni) {
                int col = bn + wn + ni * 16 + lr;
                float bv = bias ? bias[col] : 0.0f;
                #pragma unroll
                for (int r = 0; r < 4; ++r) {
                    int row = bm + wm + mi * 16 + lg * 4 + r;
                    C[(size_t)row * N + col] = acc[mi][ni][r] + bv;
                }
            }
    } else {
        unsigned short* C = (unsigned short*)Cv;
        #pragma unroll
        for (int mi = 0; mi < 4; ++mi)
            #pragma unroll
            for (int ni = 0; ni < 4; ++ni) {
                int col = bn + wn + ni * 16 + lr;
                #pragma unroll
                for (int r = 0; r < 4; ++r) {
                    int row = bm + wm + mi * 16 + lg * 4 + r;
                    C[(size_t)row * N + col] = f2bf(acc[mi][ni][r]);
                }
            }
    }
}

// ---------- flash attention ----------
// Per-tile process for one 16-row q-group of one wave.
// Swizzle: within a [64 rows][128 B] LDS tile, physical 16B-chunk = logical chunk ^ (row & 7).
__device__ __forceinline__ void attn_process(
    const unsigned short* __restrict__ Ks, const unsigned short* __restrict__ Vt,
    unsigned short* __restrict__ Psw,
    const s16x8* qf, f32x4* o, float* m_r, float* l_r,
    int s0, int q0t, int lr, int lg, bool domask)
{
    const float scale_l2e = 0.03125f * 1.44269504088896341f;  // C^-0.5 * log2(e)
    // S = Q K^T
    f32x4 S[4] = {};
    #pragma unroll
    for (int nb = 0; nb < 4; ++nb)
        #pragma unroll
        for (int ks = 0; ks < 2; ++ks) {
            s16x8 kf = *(const s16x8*)&Ks[(nb * 16 + lr) * 64 + (((ks * 4 + lg) ^ (lr & 7)) << 3)];
            S[nb] = MFMA16x16x32(qf[ks], kf, S[nb]);
        }
    // scale (+ causal mask on diagonal tiles), exp2 domain, in place
    #pragma unroll
    for (int nb = 0; nb < 4; ++nb)
        #pragma unroll
        for (int r = 0; r < 4; ++r) {
            float zv = S[nb][r] * scale_l2e;
            if (domask) {
                int scol = s0 + nb * 16 + lr;
                int qrow = q0t + lg * 4 + r;
                zv = (scol <= qrow) ? zv : -1e30f;
            }
            S[nb][r] = zv;
        }
    // online softmax: rows are (lg*4+r); reduce over lr lanes (masks 1..8 stay in lg-group)
    float alpha[4];
    #pragma unroll
    for (int r = 0; r < 4; ++r) {
        float zm = fmaxf(fmaxf(S[0][r], S[1][r]), fmaxf(S[2][r], S[3][r]));
        #pragma unroll
        for (int msk = 1; msk <= 8; msk <<= 1)
            zm = fmaxf(zm, __shfl_xor(zm, msk, 64));
        float mnew = fmaxf(m_r[r], zm);
        alpha[r] = exp2f(m_r[r] - mnew);
        m_r[r] = mnew;
    }
    float rs[4] = {0.f, 0.f, 0.f, 0.f};
    #pragma unroll
    for (int nb = 0; nb < 4; ++nb)
        #pragma unroll
        for (int r = 0; r < 4; ++r) {
            float pv = exp2f(S[nb][r] - m_r[r]);
            rs[r] += pv;
            int row = lg * 4 + r;
            Psw[row * 64 + (((nb * 2 + (lr >> 3)) ^ (row & 7)) << 3) + (lr & 7)] = f2bf(pv);
        }
    #pragma unroll
    for (int r = 0; r < 4; ++r) {
        #pragma unroll
        for (int msk = 1; msk <= 8; msk <<= 1)
            rs[r] += __shfl_xor(rs[r], msk, 64);
        l_r[r] = l_r[r] * alpha[r] + rs[r];
    }
    #pragma unroll
    for (int db = 0; db < 4; ++db)
        #pragma unroll
        for (int r = 0; r < 4; ++r)
            o[db][r] *= alpha[r];
    // P (LDS, per-wave) as A-frags; V^T as B-frags
    asm volatile("s_waitcnt lgkmcnt(0)" ::: "memory");
    __builtin_amdgcn_sched_barrier(0);
    s16x8 pf[2];
    #pragma unroll
    for (int ks2 = 0; ks2 < 2; ++ks2)
        pf[ks2] = *(const s16x8*)&Psw[lr * 64 + (((ks2 * 4 + lg) ^ (lr & 7)) << 3)];
    #pragma unroll
    for (int db = 0; db < 4; ++db)
        #pragma unroll
        for (int ks2 = 0; ks2 < 2; ++ks2) {
            s16x8 vf = *(const s16x8*)&Vt[(db * 16 + lr) * 64 + (((ks2 * 4 + lg) ^ (lr & 7)) << 3)];
            o[db] = MFMA16x16x32(pf[ks2], vf, o[db]);
        }
}

// Block = 256 threads = 4 waves; block p handles q-tiles {p, 31-p} of one (b,h):
// equal work (33 kv-tile computes) + shared K/V staging + double-buffered prefetch.
__global__ __launch_bounds__(256) void attn_kernel(
    const unsigned short* __restrict__ qkv, unsigned short* __restrict__ attn, int T)
{
    __shared__ __align__(16) unsigned short Ks[2][64 * 64];   // 16 KB
    __shared__ __align__(16) unsigned short Vt[2][64 * 64];   // 16 KB (swizzled [d][s])
    __shared__ __align__(16) unsigned short Ps[4][16 * 64];   //  8 KB (per-wave, swizzled)

    const int blk = blockIdx.x;
    const int p = blk & 15;
    const int h = (blk >> 4) & 15;
    const int b = blk >> 8;
    const int qtA = p, qtB = 31 - p;
    const int q0A = qtA * 64, q0B = qtB * 64;
    const int nkv = qtB + 1;

    const int t = threadIdx.x, w = t >> 6, l = t & 63, lr = l & 15, lg = l >> 4;
    const unsigned short* base = qkv + (size_t)b * T * 3072;
    const unsigned short* kbase = base + 1024 + h * 64;
    const unsigned short* vbase = base + 2048 + h * 64;

    // Q fragments for both q-tiles
    s16x8 qfA[2], qfB[2];
    #pragma unroll
    for (int ks = 0; ks < 2; ++ks) {
        qfA[ks] = *(const s16x8*)(base + (size_t)(q0A + w * 16 + lr) * 3072 + h * 64 + ks * 32 + lg * 8);
        qfB[ks] = *(const s16x8*)(base + (size_t)(q0B + w * 16 + lr) * 3072 + h * 64 + ks * 32 + lg * 8);
    }

    f32x4 oA[4] = {}, oB[4] = {};
    float mA[4], lA[4], mB[4], lB[4];
    #pragma unroll
    for (int r = 0; r < 4; ++r) { mA[r] = -1e30f; lA[r] = 0.f; mB[r] = -1e30f; lB[r] = 0.f; }

    // V staging: thread owns (s = t&63, d0 = (t>>6)*16), 16 values
    const int sv = t & 63, d0v = (t >> 6) << 4;
    u16x8 v0, v1;

    // ---- prologue: stage tile 0 into buffer 0 ----
    #pragma unroll
    for (int i = 0; i < 2; ++i) {
        int c = i * 256 + t, ss = c >> 3, kk = c & 7;
        GLD_LDS16(kbase + (size_t)ss * 3072 + ((kk ^ (ss & 7)) << 3), &Ks[0][c * 8]);
    }
    {
        const unsigned short* vp = vbase + (size_t)sv * 3072 + d0v;
        v0 = *(const u16x8*)vp; v1 = *(const u16x8*)(vp + 8);
    }
    #pragma unroll
    for (int j = 0; j < 8; ++j) {
        int d = d0v + j;
        Vt[0][d * 64 + ((((sv >> 3) ^ (d & 7)) << 3)) + (sv & 7)] = v0[j];
    }
    #pragma unroll
    for (int j = 0; j < 8; ++j) {
        int d = d0v + 8 + j;
        Vt[0][d * 64 + ((((sv >> 3) ^ (d & 7)) << 3)) + (sv & 7)] = v1[j];
    }
    __syncthreads();

    for (int kt = 0; kt < nkv; ++kt) {
        const int cur = kt & 1, nxt = cur ^ 1;
        const int s0 = kt * 64;
        const bool pre = (kt + 1 < nkv);
        if (pre) {
            const int s0n = s0 + 64;
            #pragma unroll
            for (int i = 0; i < 2; ++i) {
                int c = i * 256 + t, ss = c >> 3, kk = c & 7;
                GLD_LDS16(kbase + (size_t)(s0n + ss) * 3072 + ((kk ^ (ss & 7)) << 3), &Ks[nxt][c * 8]);
            }
            const unsigned short* vp = vbase + (size_t)(s0n + sv) * 3072 + d0v;
            v0 = *(const u16x8*)vp; v1 = *(const u16x8*)(vp + 8);
        }

        if (kt <= qtA)
            attn_process(Ks[cur], Vt[cur], Ps[w], qfA, oA, mA, lA,
                         s0, q0A + w * 16, lr, lg, kt == qtA);
        attn_process(Ks[cur], Vt[cur], Ps[w], qfB, oB, mB, lB,
                     s0, q0B + w * 16, lr, lg, kt == qtB);

        if (pre) {
            #pragma unroll
            for (int j = 0; j < 8; ++j) {
                int d = d0v + j;
                Vt[nxt][d * 64 + ((((sv >> 3) ^ (d & 7)) << 3)) + (sv & 7)] = v0[j];
            }
            #pragma unroll
            for (int j = 0; j < 8; ++j) {
                int d = d0v + 8 + j;
                Vt[nxt][d * 64 + ((((sv >> 3) ^ (d & 7)) << 3)) + (sv & 7)] = v1[j];
            }
        }
        __syncthreads();
    }

    // epilogue
    #pragma unroll
    for (int db = 0; db < 4; ++db)
        #pragma unroll
        for (int r = 0; r < 4; ++r) {
            int col = h * 64 + db * 16 + lr;
            int rowA = q0A + w * 16 + lg * 4 + r;
            attn[(size_t)(b * T + rowA) * 1024 + col] = f2bf(oA[db][r] / lA[r]);
            int rowB = q0B + w * 16 + lg * 4 + r;
            attn[(size_t)(b * T + rowB) * 1024 + col] = f2bf(oB[db][r] / lB[r]);
        }
}

// ---------- launch ----------
extern "C" void kernel_launch(void* const* d_in, const int* in_sizes, int n_in,
                              void* d_out, int out_size, void* d_ws, size_t ws_size,
                              hipStream_t stream) {
    const float* x  = (const float*)d_in[0];
    const float* Wq = (const float*)d_in[1];
    const float* Wk = (const float*)d_in[2];
    const float* Wv = (const float*)d_in[3];
    const float* Wp = (const float*)d_in[4];
    const float* bp = (const float*)d_in[5];
    float* out = (float*)d_out;

    const int T = 2048, C = 1024;
    const int BT = in_sizes[0] / C;      // 8192
    const int B  = BT / T;               // 4

    char* ws = (char*)d_ws;
    unsigned short* xb    = (unsigned short*)(ws);                        // 16,777,216
    unsigned short* WtQKV = (unsigned short*)(ws + 16777216);             //  6,291,456
    unsigned short* WtP   = (unsigned short*)(ws + 23068672);             //  2,097,152
    unsigned short* qkv   = (unsigned short*)(ws + 25165824);             // 50,331,648
    unsigned short* attn  = (unsigned short*)(ws + 75497472);             // 16,777,216
    (void)ws_size; (void)n_in; (void)out_size;

    cvt_x_kernel<<<(BT * C / 4 + 255) / 256, 256, 0, stream>>>(x, xb, BT * C);
    cvt_wqkv_kernel<<<4096, 256, 0, stream>>>(Wq, WtQKV, 0);
    cvt_wqkv_kernel<<<4096, 256, 0, stream>>>(Wk, WtQKV, 1);
    cvt_wqkv_kernel<<<4096, 256, 0, stream>>>(Wv, WtQKV, 2);
    cvt_wp_kernel<<<4096, 256, 0, stream>>>(Wp, WtP);

    gemm_bt_kernel<0><<<dim3(BT / 128, 3072 / 128), 256, 0, stream>>>(
        xb, WtQKV, qkv, nullptr, BT, 3072, C);

    attn_kernel<<<B * 16 * 16, 256, 0, stream>>>(qkv, attn, T);

    gemm_bt_kernel<1><<<dim3(BT / 128, 1024 / 128), 256, 0, stream>>>(
        attn, WtP, out, bp, BT, 1024, C);
}

// Round 3
// 274.007 us; speedup vs baseline: 1.6547x; 1.2238x over previous
//
#include <hip/hip_runtime.h>
#include <stdint.h>
#include <math.h>

// ---------- types ----------
typedef short s16x8 __attribute__((ext_vector_type(8)));   // 8 bf16 (4 VGPR)
typedef float f32x4 __attribute__((ext_vector_type(4)));

__device__ __forceinline__ unsigned short f2bf(float f) {
    union { float f; uint32_t u; } x; x.f = f;
    uint32_t r = x.u + 0x7FFFu + ((x.u >> 16) & 1u);   // RNE
    return (unsigned short)(r >> 16);
}

__device__ __forceinline__ uint32_t cvtpk_bf16(float lo, float hi) {
    uint32_t r;
    asm("v_cvt_pk_bf16_f32 %0, %1, %2" : "=v"(r) : "v"(lo), "v"(hi));
    return r;
}

#define GLD_LDS16(gp, lp) __builtin_amdgcn_global_load_lds( \
    (const __attribute__((address_space(1))) uint32_t*)(gp), \
    (__attribute__((address_space(3))) uint32_t*)(lp), 16, 0, 0)

#define MFMA16x16x32(a, b, c) __builtin_amdgcn_mfma_f32_16x16x32_bf16((a), (b), (c), 0, 0, 0)

// ---------- convert kernels ----------
__global__ void cvt_x_kernel(const float* __restrict__ x, unsigned short* __restrict__ xb, int n) {
    int i = (blockIdx.x * blockDim.x + threadIdx.x) * 4;
    if (i >= n) return;
    float4 v = *(const float4*)(x + i);
    unsigned short o0 = f2bf(v.x), o1 = f2bf(v.y), o2 = f2bf(v.z), o3 = f2bf(v.w);
    uint64_t packed = (uint64_t)o0 | ((uint64_t)o1 << 16) | ((uint64_t)o2 << 32) | ((uint64_t)o3 << 48);
    *(uint64_t*)(xb + i) = packed;
}

// W [16][1024][64] f32 -> Wt rows (which*1024 + h*64 + d), cols c  (B^T layout [..][1024])
__global__ void cvt_wqkv_kernel(const float* __restrict__ W, unsigned short* __restrict__ Wt, int which) {
    int id = blockIdx.x * blockDim.x + threadIdx.x;
    if (id >= 16 * 1024 * 64) return;
    int h = id >> 16, c = (id >> 6) & 1023, d = id & 63;
    Wt[(size_t)(which * 1024 + h * 64 + d) * 1024 + c] = f2bf(W[id]);
}

// Wp [1024][1024] (c, n) -> Wpt [n][c] bf16
__global__ void cvt_wp_kernel(const float* __restrict__ W, unsigned short* __restrict__ Wt) {
    int id = blockIdx.x * blockDim.x + threadIdx.x;
    if (id >= 1024 * 1024) return;
    int c = id >> 10, n = id & 1023;
    Wt[(size_t)n * 1024 + c] = f2bf(W[id]);
}

// ---------- GEMM: C[M][N] = A[M][K] * Bt[N][K]^T ----------
// MODE 0: QKV — cols [0,2048) -> qkv2 bf16 [M][2048]; cols [2048,3072) -> vT[(b,h,d)][t] bf16
// MODE 1: f32 out + bias
template<int MODE>
__global__ __launch_bounds__(256) void gemm_bt_kernel(
    const unsigned short* __restrict__ A, const unsigned short* __restrict__ Bt,
    void* __restrict__ Cv, unsigned short* __restrict__ vT,
    const float* __restrict__ bias, int M, int N, int K)
{
    constexpr int BK = 64;
    __shared__ __align__(16) unsigned short As[128 * BK];
    __shared__ __align__(16) unsigned short Bs[128 * BK];
    const int t = threadIdx.x, w = t >> 6, l = t & 63, lr = l & 15, lg = l >> 4;
    const int wm = (w >> 1) << 6, wn = (w & 1) << 6;
    const int bm = blockIdx.x << 7, bn = blockIdx.y << 7;
    const unsigned short* Ab = A + (size_t)bm * K;
    const unsigned short* Bb = Bt + (size_t)bn * K;
    f32x4 acc[4][4] = {};
    for (int k0 = 0; k0 < K; k0 += BK) {
        __syncthreads();
        #pragma unroll
        for (int i = 0; i < 4; ++i) {
            int c = i * 256 + t;
            GLD_LDS16(Ab + (size_t)(c >> 3) * K + k0 + ((c & 7) << 3), As + c * 8);
        }
        #pragma unroll
        for (int i = 0; i < 4; ++i) {
            int c = i * 256 + t;
            GLD_LDS16(Bb + (size_t)(c >> 3) * K + k0 + ((c & 7) << 3), Bs + c * 8);
        }
        __syncthreads();
        #pragma unroll
        for (int ks = 0; ks < 2; ++ks) {
            s16x8 af[4], bfr[4];
            #pragma unroll
            for (int mi = 0; mi < 4; ++mi)
                af[mi] = *(const s16x8*)&As[(wm + mi * 16 + lr) * BK + ks * 32 + lg * 8];
            #pragma unroll
            for (int ni = 0; ni < 4; ++ni)
                bfr[ni] = *(const s16x8*)&Bs[(wn + ni * 16 + lr) * BK + ks * 32 + lg * 8];
            #pragma unroll
            for (int mi = 0; mi < 4; ++mi)
                #pragma unroll
                for (int ni = 0; ni < 4; ++ni)
                    acc[mi][ni] = MFMA16x16x32(af[mi], bfr[ni], acc[mi][ni]);
        }
    }
    if (MODE == 1) {
        float* C = (float*)Cv;
        #pragma unroll
        for (int mi = 0; mi < 4; ++mi)
            #pragma unroll
            for (int ni = 0; ni < 4; ++ni) {
                int col = bn + wn + ni * 16 + lr;
                float bv = bias ? bias[col] : 0.0f;
                #pragma unroll
                for (int r = 0; r < 4; ++r) {
                    int row = bm + wm + mi * 16 + lg * 4 + r;
                    C[(size_t)row * N + col] = acc[mi][ni][r] + bv;
                }
            }
    } else {
        unsigned short* Cq = (unsigned short*)Cv;
        const bool isV = (bn >= 2048);            // block-uniform (2048 % 128 == 0)
        #pragma unroll
        for (int mi = 0; mi < 4; ++mi)
            #pragma unroll
            for (int ni = 0; ni < 4; ++ni) {
                int col = bn + wn + ni * 16 + lr;
                int row0 = bm + wm + mi * 16 + lg * 4;
                if (!isV) {
                    #pragma unroll
                    for (int r = 0; r < 4; ++r)
                        Cq[(size_t)(row0 + r) * 2048 + col] = f2bf(acc[mi][ni][r]);
                } else {
                    int h = (col >> 6) & 15, d = col & 63;
                    size_t vb = ((size_t)((row0 >> 11) * 16 + h) * 64 + d) * 2048 + (row0 & 2047);
                    uint32_t u0 = (uint32_t)f2bf(acc[mi][ni][0]) | ((uint32_t)f2bf(acc[mi][ni][1]) << 16);
                    uint32_t u1 = (uint32_t)f2bf(acc[mi][ni][2]) | ((uint32_t)f2bf(acc[mi][ni][3]) << 16);
                    *(uint32_t*)&vT[vb]     = u0;
                    *(uint32_t*)&vT[vb + 2] = u1;
                }
            }
    }
}

// ---------- flash attention ----------
// Swapped-QK structure: each lane owns q-row (q = q0t + lr); S^T = mfma(K, Q).
// LDS swizzle (all tiles [64 rows][128 B]): physical 16B-chunk = logical chunk ^ (row & 7).
__device__ __forceinline__ void attn_process(
    const unsigned short* __restrict__ Ksb, const unsigned short* __restrict__ Vtb,
    unsigned short* __restrict__ Psw,
    const s16x8* qf, f32x4* o, float& m_r, float& l_r,
    int qms, int lr, int lg, bool domask)
{
    const float scale_l2e = 0.03125f * 1.44269504088896341f;  // C^-0.5 * log2(e)
    f32x4 S[4] = {};
    __builtin_amdgcn_s_setprio(1);
    #pragma unroll
    for (int nb = 0; nb < 4; ++nb)
        #pragma unroll
        for (int ks = 0; ks < 2; ++ks) {
            s16x8 kf = *(const s16x8*)&Ksb[(nb * 16 + lr) * 64 + (((ks * 4 + lg) ^ (lr & 7)) << 3)];
            S[nb] = MFMA16x16x32(kf, qf[ks], S[nb]);   // S^T: row = s (lg*4+r), col = q (lr)
        }
    __builtin_amdgcn_s_setprio(0);
    #pragma unroll
    for (int nb = 0; nb < 4; ++nb)
        #pragma unroll
        for (int r = 0; r < 4; ++r) {
            float zv = S[nb][r] * scale_l2e;
            if (domask) zv = (nb * 16 + lg * 4 + r <= qms) ? zv : -1e30f;
            S[nb][r] = zv;
        }
    // row stats: 15 in-lane max + reduce over the 4 lg-lanes (xor 16, 32)
    float zm = fmaxf(fmaxf(fmaxf(S[0][0], S[0][1]), fmaxf(S[0][2], S[0][3])),
                     fmaxf(fmaxf(S[1][0], S[1][1]), fmaxf(S[1][2], S[1][3])));
    zm = fmaxf(zm, fmaxf(fmaxf(fmaxf(S[2][0], S[2][1]), fmaxf(S[2][2], S[2][3])),
                         fmaxf(fmaxf(S[3][0], S[3][1]), fmaxf(S[3][2], S[3][3]))));
    zm = fmaxf(zm, __shfl_xor(zm, 16, 64));
    zm = fmaxf(zm, __shfl_xor(zm, 32, 64));
    const bool defer = (__all(zm <= m_r + 8.0f) != 0);   // T13: skip rescale, P bounded by 2^8
    float alpha = 1.0f;
    if (!defer) {
        float mnew = fmaxf(m_r, zm);
        alpha = exp2f(m_r - mnew);
        m_r = mnew;
    }
    float rs = 0.0f;
    #pragma unroll
    for (int nb = 0; nb < 4; ++nb) {
        #pragma unroll
        for (int r = 0; r < 4; ++r) {
            float pv = exp2f(S[nb][r] - m_r);
            rs += pv;
            S[nb][r] = pv;
        }
        uint32_t p0 = cvtpk_bf16(S[nb][0], S[nb][1]);
        uint32_t p1 = cvtpk_bf16(S[nb][2], S[nb][3]);
        int chunk = (nb * 2 + (lg >> 1)) ^ (lr & 7);
        uint32_t* wp = (uint32_t*)((char*)Psw + lr * 128 + chunk * 16 + (lg & 1) * 8);
        wp[0] = p0; wp[1] = p1;
    }
    rs += __shfl_xor(rs, 16, 64);
    rs += __shfl_xor(rs, 32, 64);
    l_r = defer ? (l_r + rs) : (l_r * alpha + rs);
    if (!defer) {
        #pragma unroll
        for (int r = 0; r < 4; ++r) {
            float ab = __shfl(alpha, lg * 4 + r, 64);   // alpha for o-row q = lg*4+r
            #pragma unroll
            for (int db = 0; db < 4; ++db) o[db][r] *= ab;
        }
    }
    asm volatile("s_waitcnt lgkmcnt(0)" ::: "memory");
    __builtin_amdgcn_sched_barrier(0);
    s16x8 pf[2];
    #pragma unroll
    for (int ks = 0; ks < 2; ++ks)
        pf[ks] = *(const s16x8*)&Psw[lr * 64 + (((ks * 4 + lg) ^ (lr & 7)) << 3)];
    __builtin_amdgcn_s_setprio(1);
    #pragma unroll
    for (int db = 0; db < 4; ++db)
        #pragma unroll
        for (int ks = 0; ks < 2; ++ks) {
            s16x8 vf = *(const s16x8*)&Vtb[(db * 16 + lr) * 64 + (((ks * 4 + lg) ^ (lr & 7)) << 3)];
            o[db] = MFMA16x16x32(pf[ks], vf, o[db]);
        }
    __builtin_amdgcn_s_setprio(0);
}

// Block = 256 threads = 4 waves; block p: q-tiles {p, 31-p} of one (b,h).
__global__ __launch_bounds__(256) void attn_kernel(
    const unsigned short* __restrict__ qkv2, const unsigned short* __restrict__ vT,
    unsigned short* __restrict__ attnO, int T)
{
    __shared__ __align__(16) unsigned short Ks[2][64 * 64];   // [s][d], swizzled, 16 KB
    __shared__ __align__(16) unsigned short Vt[2][64 * 64];   // [d][s], swizzled, 16 KB
    __shared__ __align__(16) unsigned short Ps[4][16 * 64];   // per-wave [q][s], swizzled, 8 KB

    const int blk = blockIdx.x;
    const int p = blk & 15, h = (blk >> 4) & 15, b = blk >> 8;
    const int qtA = p, qtB = 31 - p;
    const int q0A = qtA * 64, q0B = qtB * 64;
    const int nkv = qtB + 1;
    const int t = threadIdx.x, w = t >> 6, l = t & 63, lr = l & 15, lg = l >> 4;

    const unsigned short* qbase = qkv2 + (size_t)b * T * 2048;
    const unsigned short* kbase = qbase + 1024 + h * 64;
    const unsigned short* vtb   = vT + (size_t)(b * 16 + h) * 64 * 2048;

    s16x8 qfA[2], qfB[2];
    #pragma unroll
    for (int ks = 0; ks < 2; ++ks) {
        qfA[ks] = *(const s16x8*)(qbase + (size_t)(q0A + w * 16 + lr) * 2048 + h * 64 + ks * 32 + lg * 8);
        qfB[ks] = *(const s16x8*)(qbase + (size_t)(q0B + w * 16 + lr) * 2048 + h * 64 + ks * 32 + lg * 8);
    }

    f32x4 oA[4] = {}, oB[4] = {};
    float mA = -1e30f, lA = 0.0f, mB = -1e30f, lB = 0.0f;

    auto STAGE = [&](int buf, int s0) {
        #pragma unroll
        for (int i = 0; i < 2; ++i) {
            int c = i * 256 + t, ss = c >> 3, kk = c & 7;
            GLD_LDS16(kbase + (size_t)(s0 + ss) * 2048 + ((kk ^ (ss & 7)) << 3), &Ks[buf][c * 8]);
        }
        #pragma unroll
        for (int i = 0; i < 2; ++i) {
            int c = i * 256 + t, dd = c >> 3, kk = c & 7;
            GLD_LDS16(vtb + (size_t)dd * 2048 + s0 + ((kk ^ (dd & 7)) << 3), &Vt[buf][c * 8]);
        }
    };

    STAGE(0, 0);
    __syncthreads();

    for (int kt = 0; kt < nkv; ++kt) {
        const int cur = kt & 1, nxt = cur ^ 1;
        if (kt + 1 < nkv) STAGE(nxt, (kt + 1) * 64);
        if (kt <= qtA)
            attn_process(Ks[cur], Vt[cur], Ps[w], qfA, oA, mA, lA,
                         (q0A + w * 16 + lr) - kt * 64, lr, lg, kt == qtA);
        attn_process(Ks[cur], Vt[cur], Ps[w], qfB, oB, mB, lB,
                     (q0B + w * 16 + lr) - kt * 64, lr, lg, kt == qtB);
        __syncthreads();
    }

    // epilogue: broadcast l from lane (q = lr) to o-rows (q = lg*4+r), normalize, store
    float lbA[4], lbB[4];
    #pragma unroll
    for (int r = 0; r < 4; ++r) {
        lbA[r] = __shfl(lA, lg * 4 + r, 64);
        lbB[r] = __shfl(lB, lg * 4 + r, 64);
    }
    #pragma unroll
    for (int db = 0; db < 4; ++db)
        #pragma unroll
        for (int r = 0; r < 4; ++r) {
            int col = h * 64 + db * 16 + lr;
            int rowA = q0A + w * 16 + lg * 4 + r;
            attnO[(size_t)(b * T + rowA) * 1024 + col] = f2bf(oA[db][r] / lbA[r]);
            int rowB = q0B + w * 16 + lg * 4 + r;
            attnO[(size_t)(b * T + rowB) * 1024 + col] = f2bf(oB[db][r] / lbB[r]);
        }
}

// ---------- launch ----------
extern "C" void kernel_launch(void* const* d_in, const int* in_sizes, int n_in,
                              void* d_out, int out_size, void* d_ws, size_t ws_size,
                              hipStream_t stream) {
    const float* x  = (const float*)d_in[0];
    const float* Wq = (const float*)d_in[1];
    const float* Wk = (const float*)d_in[2];
    const float* Wv = (const float*)d_in[3];
    const float* Wp = (const float*)d_in[4];
    const float* bp = (const float*)d_in[5];
    float* out = (float*)d_out;

    const int T = 2048, C = 1024;
    const int BT = in_sizes[0] / C;      // 8192
    const int B  = BT / T;               // 4

    // workspace layout (bytes), total 92,274,688
    char* ws = (char*)d_ws;
    unsigned short* xb    = (unsigned short*)(ws);                        // 16,777,216
    unsigned short* WtQKV = (unsigned short*)(ws + 16777216);             //  6,291,456
    unsigned short* WtP   = (unsigned short*)(ws + 23068672);             //  2,097,152
    unsigned short* qkv2  = (unsigned short*)(ws + 25165824);             // 33,554,432 [8192][2048]
    unsigned short* vT    = (unsigned short*)(ws + 58720256);             // 16,777,216 [(b,h,d)][2048]
    unsigned short* attn  = (unsigned short*)(ws + 75497472);             // 16,777,216
    (void)ws_size; (void)n_in; (void)out_size;

    cvt_x_kernel<<<(BT * C / 4 + 255) / 256, 256, 0, stream>>>(x, xb, BT * C);
    cvt_wqkv_kernel<<<4096, 256, 0, stream>>>(Wq, WtQKV, 0);
    cvt_wqkv_kernel<<<4096, 256, 0, stream>>>(Wk, WtQKV, 1);
    cvt_wqkv_kernel<<<4096, 256, 0, stream>>>(Wv, WtQKV, 2);
    cvt_wp_kernel<<<4096, 256, 0, stream>>>(Wp, WtP);

    // QKV projection: Q,K -> qkv2 [8192][2048]; V -> vT transposed
    gemm_bt_kernel<0><<<dim3(BT / 128, 3072 / 128), 256, 0, stream>>>(
        xb, WtQKV, qkv2, vT, nullptr, BT, 3072, C);

    attn_kernel<<<B * 16 * 16, 256, 0, stream>>>(qkv2, vT, attn, T);

    gemm_bt_kernel<1><<<dim3(BT / 128, 1024 / 128), 256, 0, stream>>>(
        attn, WtP, out, nullptr, bp, BT, 1024, C);
}

// Round 4
// 242.906 us; speedup vs baseline: 1.8666x; 1.1280x over previous
//
#include <hip/hip_runtime.h>
#include <stdint.h>
#include <math.h>

// ---------- types ----------
typedef short s16x8 __attribute__((ext_vector_type(8)));   // 8 bf16 (4 VGPR)
typedef float f32x4 __attribute__((ext_vector_type(4)));
typedef float f32x16 __attribute__((ext_vector_type(16)));

__device__ __forceinline__ unsigned short f2bf(float f) {
    union { float f; uint32_t u; } x; x.f = f;
    uint32_t r = x.u + 0x7FFFu + ((x.u >> 16) & 1u);   // RNE
    return (unsigned short)(r >> 16);
}

__device__ __forceinline__ uint32_t cvtpk_bf16(float lo, float hi) {
    uint32_t r;
    asm("v_cvt_pk_bf16_f32 %0, %1, %2" : "=v"(r) : "v"(lo), "v"(hi));
    return r;
}

#define GLD_LDS16(gp, lp) __builtin_amdgcn_global_load_lds( \
    (const __attribute__((address_space(1))) uint32_t*)(gp), \
    (__attribute__((address_space(3))) uint32_t*)(lp), 16, 0, 0)

#define MFMA16x16x32(a, b, c) __builtin_amdgcn_mfma_f32_16x16x32_bf16((a), (b), (c), 0, 0, 0)
#define MFMA32x32x16(a, b, c) __builtin_amdgcn_mfma_f32_32x32x16_bf16((a), (b), (c), 0, 0, 0)

// lane-half exchange: x <- {a.low(self) | partner(hi0).b}, y <- {partner(hi1).a | b.high(self)}
__device__ __forceinline__ void plswap(uint32_t a, uint32_t b, int hi, uint32_t& x, uint32_t& y) {
#if __has_builtin(__builtin_amdgcn_permlane32_swap)
    auto r = __builtin_amdgcn_permlane32_swap(a, b, false, false);
    x = (uint32_t)r[0]; y = (uint32_t)r[1];
#else
    uint32_t as = (uint32_t)__shfl_xor((int)a, 32, 64);
    uint32_t bs = (uint32_t)__shfl_xor((int)b, 32, 64);
    x = hi ? bs : a;
    y = hi ? b : as;
#endif
}

// ---------- convert kernels ----------
__global__ void cvt_x_kernel(const float* __restrict__ x, unsigned short* __restrict__ xb, int n) {
    int i = (blockIdx.x * blockDim.x + threadIdx.x) * 4;
    if (i >= n) return;
    float4 v = *(const float4*)(x + i);
    unsigned short o0 = f2bf(v.x), o1 = f2bf(v.y), o2 = f2bf(v.z), o3 = f2bf(v.w);
    uint64_t packed = (uint64_t)o0 | ((uint64_t)o1 << 16) | ((uint64_t)o2 << 32) | ((uint64_t)o3 << 48);
    *(uint64_t*)(xb + i) = packed;
}

// W [16][1024][64] f32 -> Wt rows (which*1024 + h*64 + d), cols c  (B^T layout [..][1024])
__global__ void cvt_wqkv_kernel(const float* __restrict__ W, unsigned short* __restrict__ Wt, int which) {
    int id = blockIdx.x * blockDim.x + threadIdx.x;
    if (id >= 16 * 1024 * 64) return;
    int h = id >> 16, c = (id >> 6) & 1023, d = id & 63;
    Wt[(size_t)(which * 1024 + h * 64 + d) * 1024 + c] = f2bf(W[id]);
}

// Wp [1024][1024] (c, n) -> Wpt [n][c] bf16
__global__ void cvt_wp_kernel(const float* __restrict__ W, unsigned short* __restrict__ Wt) {
    int id = blockIdx.x * blockDim.x + threadIdx.x;
    if (id >= 1024 * 1024) return;
    int c = id >> 10, n = id & 1023;
    Wt[(size_t)n * 1024 + c] = f2bf(W[id]);
}

// ---------- GEMM: C[M][N] = A[M][K] * Bt[N][K]^T ----------
// MODE 0: QKV — cols [0,1024) Q (pre-scaled by C^-0.5*log2e) + [1024,2048) K -> qkv2 [M][2048];
//         cols [2048,3072) -> vT[(b,h,d)][t]
// MODE 1: f32 out + bias
template<int MODE>
__global__ __launch_bounds__(256) void gemm_bt_kernel(
    const unsigned short* __restrict__ A, const unsigned short* __restrict__ Bt,
    void* __restrict__ Cv, unsigned short* __restrict__ vT,
    const float* __restrict__ bias, int M, int N, int K)
{
    constexpr int BK = 64;
    __shared__ __align__(16) unsigned short As[128 * BK];
    __shared__ __align__(16) unsigned short Bs[128 * BK];
    const int t = threadIdx.x, w = t >> 6, l = t & 63, lr = l & 15, lg = l >> 4;
    const int wm = (w >> 1) << 6, wn = (w & 1) << 6;
    const int bm = blockIdx.x << 7, bn = blockIdx.y << 7;
    const unsigned short* Ab = A + (size_t)bm * K;
    const unsigned short* Bb = Bt + (size_t)bn * K;
    f32x4 acc[4][4] = {};
    for (int k0 = 0; k0 < K; k0 += BK) {
        __syncthreads();
        #pragma unroll
        for (int i = 0; i < 4; ++i) {
            int c = i * 256 + t;
            GLD_LDS16(Ab + (size_t)(c >> 3) * K + k0 + ((c & 7) << 3), As + c * 8);
        }
        #pragma unroll
        for (int i = 0; i < 4; ++i) {
            int c = i * 256 + t;
            GLD_LDS16(Bb + (size_t)(c >> 3) * K + k0 + ((c & 7) << 3), Bs + c * 8);
        }
        __syncthreads();
        #pragma unroll
        for (int ks = 0; ks < 2; ++ks) {
            s16x8 af[4], bfr[4];
            #pragma unroll
            for (int mi = 0; mi < 4; ++mi)
                af[mi] = *(const s16x8*)&As[(wm + mi * 16 + lr) * BK + ks * 32 + lg * 8];
            #pragma unroll
            for (int ni = 0; ni < 4; ++ni)
                bfr[ni] = *(const s16x8*)&Bs[(wn + ni * 16 + lr) * BK + ks * 32 + lg * 8];
            #pragma unroll
            for (int mi = 0; mi < 4; ++mi)
                #pragma unroll
                for (int ni = 0; ni < 4; ++ni)
                    acc[mi][ni] = MFMA16x16x32(af[mi], bfr[ni], acc[mi][ni]);
        }
    }
    if (MODE == 1) {
        float* C = (float*)Cv;
        #pragma unroll
        for (int mi = 0; mi < 4; ++mi)
            #pragma unroll
            for (int ni = 0; ni < 4; ++ni) {
                int col = bn + wn + ni * 16 + lr;
                float bv = bias ? bias[col] : 0.0f;
                #pragma unroll
                for (int r = 0; r < 4; ++r) {
                    int row = bm + wm + mi * 16 + lg * 4 + r;
                    C[(size_t)row * N + col] = acc[mi][ni][r] + bv;
                }
            }
    } else {
        unsigned short* Cq = (unsigned short*)Cv;
        const bool isV = (bn >= 2048);                 // block-uniform
        const float sc = (bn < 1024) ? (0.03125f * 1.44269504088896341f) : 1.0f;  // pre-scale Q
        #pragma unroll
        for (int mi = 0; mi < 4; ++mi)
            #pragma unroll
            for (int ni = 0; ni < 4; ++ni) {
                int col = bn + wn + ni * 16 + lr;
                int row0 = bm + wm + mi * 16 + lg * 4;
                if (!isV) {
                    #pragma unroll
                    for (int r = 0; r < 4; ++r)
                        Cq[(size_t)(row0 + r) * 2048 + col] = f2bf(acc[mi][ni][r] * sc);
                } else {
                    int h = (col >> 6) & 15, d = col & 63;
                    size_t vb = ((size_t)((row0 >> 11) * 16 + h) * 64 + d) * 2048 + (row0 & 2047);
                    uint32_t u0 = (uint32_t)f2bf(acc[mi][ni][0]) | ((uint32_t)f2bf(acc[mi][ni][1]) << 16);
                    uint32_t u1 = (uint32_t)f2bf(acc[mi][ni][2]) | ((uint32_t)f2bf(acc[mi][ni][3]) << 16);
                    *(uint32_t*)&vT[vb]     = u0;
                    *(uint32_t*)&vT[vb + 2] = u1;
                }
            }
    }
}

// ---------- flash attention (32x32 MFMA, in-register P) ----------
// S^T = mfma(K, Q): col q = lane&31 (lane owns one q-row), row s = (r&3)+8*(r>>2)+4*hi (+32*sblk).
// LDS tiles [64 rows][128 B], chunk swizzle: phys = logical ^ (row & 7).
__device__ __forceinline__ void proc32(
    const unsigned short* __restrict__ Ksb, const unsigned short* __restrict__ Vtb,
    const s16x8* qf, f32x16* o, float& m_r, float& l_r,
    int qms, bool domask, int lq, int hi)
{
    f32x16 S[2] = {};
    __builtin_amdgcn_s_setprio(1);
    #pragma unroll
    for (int sblk = 0; sblk < 2; ++sblk)
        #pragma unroll
        for (int kd = 0; kd < 4; ++kd) {
            int row = sblk * 32 + lq;
            s16x8 kf = *(const s16x8*)&Ksb[row * 64 + (((2 * kd + hi) ^ (row & 7)) << 3)];
            S[sblk] = MFMA32x32x16(kf, qf[kd], S[sblk]);
        }
    __builtin_amdgcn_s_setprio(0);
    if (domask) {
        #pragma unroll
        for (int sblk = 0; sblk < 2; ++sblk)
            #pragma unroll
            for (int r = 0; r < 16; ++r) {
                int s_loc = sblk * 32 + (r & 3) + 8 * (r >> 2) + 4 * hi;
                S[sblk][r] = (s_loc <= qms) ? S[sblk][r] : -1e30f;
            }
    }
    // row max: in-lane tree over 32 + 1 shuffle (lane^32 holds same q, other s-half)
    float zm = fmaxf(S[0][0], S[0][1]);
    #pragma unroll
    for (int r = 2; r < 16; ++r) zm = fmaxf(zm, S[0][r]);
    #pragma unroll
    for (int r = 0; r < 16; ++r) zm = fmaxf(zm, S[1][r]);
    zm = fmaxf(zm, __shfl_xor(zm, 32, 64));
    const bool defer = (__all(zm <= m_r + 8.0f) != 0);   // T13
    if (!defer) {
        float mn = fmaxf(m_r, zm);
        float alpha = exp2f(m_r - mn);
        m_r = mn;
        l_r *= alpha;
        o[0] *= alpha;
        o[1] *= alpha;
    }
    float rs = 0.0f;
    uint32_t pk[2][8];
    #pragma unroll
    for (int sblk = 0; sblk < 2; ++sblk) {
        #pragma unroll
        for (int r = 0; r < 16; ++r) {
            float pv = exp2f(S[sblk][r] - m_r);
            S[sblk][r] = pv;
            rs += pv;
        }
        #pragma unroll
        for (int hh = 0; hh < 8; ++hh)
            pk[sblk][hh] = cvtpk_bf16(S[sblk][2 * hh], S[sblk][2 * hh + 1]);
    }
    rs += __shfl_xor(rs, 32, 64);
    l_r += rs;
    // pf[ks2]: B-frag P^T, col q = lane&31, k = s = 16*ks2 + 8*hi + j
    s16x8 pf[4];
    #pragma unroll
    for (int ks2 = 0; ks2 < 4; ++ks2) {
        int sb = ks2 >> 1, Bh = 4 * (ks2 & 1);
        uint32_t w0, w1, w2, w3;
        plswap(pk[sb][Bh + 0], pk[sb][Bh + 2], hi, w0, w2);
        plswap(pk[sb][Bh + 1], pk[sb][Bh + 3], hi, w1, w3);
        union { uint32_t u[4]; s16x8 v; } pu;
        pu.u[0] = w0; pu.u[1] = w1; pu.u[2] = w2; pu.u[3] = w3;
        pf[ks2] = pu.v;
    }
    __builtin_amdgcn_s_setprio(1);
    #pragma unroll
    for (int dblk = 0; dblk < 2; ++dblk)
        #pragma unroll
        for (int ks2 = 0; ks2 < 4; ++ks2) {
            int row = dblk * 32 + lq;
            s16x8 vf = *(const s16x8*)&Vtb[row * 64 + (((2 * ks2 + hi) ^ (row & 7)) << 3)];
            o[dblk] = MFMA32x32x16(vf, pf[ks2], o[dblk]);
        }
    __builtin_amdgcn_s_setprio(0);
}

// Block = 256 threads = 4 waves; block p: 128-row q-tiles {p, 15-p} of one (b,h);
// wave w owns rows [q0+32w, q0+32w+32) of each tile.
__global__ __launch_bounds__(256) void attn_kernel(
    const unsigned short* __restrict__ qkv2, const unsigned short* __restrict__ vT,
    unsigned short* __restrict__ attnO, int T)
{
    __shared__ __align__(16) unsigned short Ks[2][64 * 64];   // [s][d], swizzled, 16 KB
    __shared__ __align__(16) unsigned short Vt[2][64 * 64];   // [d][s], swizzled, 16 KB

    const int blk = blockIdx.x;
    const int p = blk & 7, h = (blk >> 3) & 15, b = blk >> 7;
    const int q0A = p * 128, q0B = (15 - p) * 128;
    const int nkv = 2 * (15 - p) + 2;

    const int t = threadIdx.x, w = t >> 6, l = t & 63, lq = l & 31, hi = l >> 5;
    const int cA = q0A + 32 * w, cB = q0B + 32 * w;
    const int lastA = (cA + 31) >> 6, lastB = (cB + 31) >> 6;

    const unsigned short* qbase = qkv2 + (size_t)b * T * 2048;
    const unsigned short* kbase = qbase + 1024 + h * 64;
    const unsigned short* vtb   = vT + (size_t)(b * 16 + h) * 64 * 2048;

    s16x8 qfA[4], qfB[4];
    #pragma unroll
    for (int kd = 0; kd < 4; ++kd) {
        qfA[kd] = *(const s16x8*)(qbase + (size_t)(cA + lq) * 2048 + h * 64 + kd * 16 + hi * 8);
        qfB[kd] = *(const s16x8*)(qbase + (size_t)(cB + lq) * 2048 + h * 64 + kd * 16 + hi * 8);
    }

    f32x16 oA[2] = {}, oB[2] = {};
    float mA = -1e30f, lA = 0.0f, mB = -1e30f, lB = 0.0f;

    auto STAGE = [&](int buf, int s0) {
        #pragma unroll
        for (int i = 0; i < 2; ++i) {
            int c = i * 256 + t, ss = c >> 3, kk = c & 7;
            GLD_LDS16(kbase + (size_t)(s0 + ss) * 2048 + ((kk ^ (ss & 7)) << 3), &Ks[buf][c * 8]);
        }
        #pragma unroll
        for (int i = 0; i < 2; ++i) {
            int c = i * 256 + t, dd = c >> 3, kk = c & 7;
            GLD_LDS16(vtb + (size_t)dd * 2048 + s0 + ((kk ^ (dd & 7)) << 3), &Vt[buf][c * 8]);
        }
    };

    STAGE(0, 0);
    __syncthreads();

    for (int kt = 0; kt < nkv; ++kt) {
        const int cur = kt & 1, nxt = cur ^ 1;
        if (kt + 1 < nkv) STAGE(nxt, (kt + 1) * 64);
        if (kt <= lastA)
            proc32(Ks[cur], Vt[cur], qfA, oA, mA, lA, cA + lq - kt * 64, kt == lastA, lq, hi);
        if (kt <= lastB)
            proc32(Ks[cur], Vt[cur], qfB, oB, mB, lB, cB + lq - kt * 64, kt == lastB, lq, hi);
        __syncthreads();
    }

    // epilogue: O^T[d][q] — lane owns column q; d = (r&3)+8*(r>>2)+4*hi (+32*dblk)
    {
        float invA = 1.0f / lA, invB = 1.0f / lB;
        #pragma unroll
        for (int dblk = 0; dblk < 2; ++dblk)
            #pragma unroll
            for (int r = 0; r < 16; r += 2) {
                int d = dblk * 32 + (r & 3) + 8 * (r >> 2) + 4 * hi;
                size_t cb = (size_t)h * 64 + d;
                uint32_t ua = cvtpk_bf16(oA[dblk][r] * invA, oA[dblk][r + 1] * invA);
                *(uint32_t*)&attnO[(size_t)(b * T + cA + lq) * 1024 + cb] = ua;
                uint32_t ub = cvtpk_bf16(oB[dblk][r] * invB, oB[dblk][r + 1] * invB);
                *(uint32_t*)&attnO[(size_t)(b * T + cB + lq) * 1024 + cb] = ub;
            }
    }
}

// ---------- launch ----------
extern "C" void kernel_launch(void* const* d_in, const int* in_sizes, int n_in,
                              void* d_out, int out_size, void* d_ws, size_t ws_size,
                              hipStream_t stream) {
    const float* x  = (const float*)d_in[0];
    const float* Wq = (const float*)d_in[1];
    const float* Wk = (const float*)d_in[2];
    const float* Wv = (const float*)d_in[3];
    const float* Wp = (const float*)d_in[4];
    const float* bp = (const float*)d_in[5];
    float* out = (float*)d_out;

    const int T = 2048, C = 1024;
    const int BT = in_sizes[0] / C;      // 8192
    const int B  = BT / T;               // 4

    // workspace layout (bytes), total 92,274,688
    char* ws = (char*)d_ws;
    unsigned short* xb    = (unsigned short*)(ws);                        // 16,777,216
    unsigned short* WtQKV = (unsigned short*)(ws + 16777216);             //  6,291,456
    unsigned short* WtP   = (unsigned short*)(ws + 23068672);             //  2,097,152
    unsigned short* qkv2  = (unsigned short*)(ws + 25165824);             // 33,554,432 [8192][2048]
    unsigned short* vT    = (unsigned short*)(ws + 58720256);             // 16,777,216 [(b,h,d)][2048]
    unsigned short* attn  = (unsigned short*)(ws + 75497472);             // 16,777,216
    (void)ws_size; (void)n_in; (void)out_size;

    cvt_x_kernel<<<(BT * C / 4 + 255) / 256, 256, 0, stream>>>(x, xb, BT * C);
    cvt_wqkv_kernel<<<4096, 256, 0, stream>>>(Wq, WtQKV, 0);
    cvt_wqkv_kernel<<<4096, 256, 0, stream>>>(Wk, WtQKV, 1);
    cvt_wqkv_kernel<<<4096, 256, 0, stream>>>(Wv, WtQKV, 2);
    cvt_wp_kernel<<<4096, 256, 0, stream>>>(Wp, WtP);

    // QKV projection: Q (pre-scaled), K -> qkv2 [8192][2048]; V -> vT transposed
    gemm_bt_kernel<0><<<dim3(BT / 128, 3072 / 128), 256, 0, stream>>>(
        xb, WtQKV, qkv2, vT, nullptr, BT, 3072, C);

    attn_kernel<<<B * 16 * 8, 256, 0, stream>>>(qkv2, vT, attn, T);

    gemm_bt_kernel<1><<<dim3(BT / 128, 1024 / 128), 256, 0, stream>>>(
        attn, WtP, out, nullptr, bp, BT, 1024, C);
}